// Round 3
// baseline (604.716 us; speedup 1.0000x reference)
//
#include <hip/hip_runtime.h>

// JPEG decode, fully fused: dequant + separable 8x8 IDCT + unblock +
// 2x chroma upsample + YCbCr->RGB + clip/255, one kernel, no workspace.
//
// Fixed problem size: B=8, H=2048, W=2048.
// R3: tile 16 rows x 256 cols per 256-thread block, grid (8,128,8).
//  - no coef LDS staging: pass-1 IDCT reads coeffs straight from global
//    (8 lanes share each 16B -> one coalesced request), dequant inline
//  - one wave per output row in the store phase: every store instruction
//    is a single contiguous 1 KB burst per plane
//  - XCD-chunked swizzle: each XCD owns 16 contiguous row-stripes so
//    adjacent tiles share an L2 -> write-combining before HBM
//  - 2 syncthreads total; all 256 threads active in chroma phase
//  - plain (cached) stores so L2 can merge neighboring tiles' lines

#define H 2048
#define W 2048
#define TW_TILES 8      // 256-wide column chunks
#define TH_TILES 128    // 16-row stripes

typedef float f32x4 __attribute__((ext_vector_type(4)));

// CT[x][u] = cos((2u+1)*x*pi/16), float32-rounded.
// Bit-identical to dct_tensor[x,0,u,0] (c[0][0]==1.0f exactly).
constexpr float CT[8][8] = {
    {  1.0f,                   1.0f,                   1.0f,                   1.0f,
       1.0f,                   1.0f,                   1.0f,                   1.0f },
    {  0.980785280403230449f,  0.831469612302545237f,  0.555570233019602225f,  0.195090322016128268f,
      -0.195090322016128268f, -0.555570233019602225f, -0.831469612302545237f, -0.980785280403230449f },
    {  0.923879532511286756f,  0.382683432365089772f, -0.382683432365089772f, -0.923879532511286756f,
      -0.923879532511286756f, -0.382683432365089772f,  0.382683432365089772f,  0.923879532511286756f },
    {  0.831469612302545237f, -0.195090322016128268f, -0.980785280403230449f, -0.555570233019602225f,
       0.555570233019602225f,  0.980785280403230449f,  0.195090322016128268f, -0.831469612302545237f },
    {  0.707106781186547524f, -0.707106781186547524f, -0.707106781186547524f,  0.707106781186547524f,
       0.707106781186547524f, -0.707106781186547524f, -0.707106781186547524f,  0.707106781186547524f },
    {  0.555570233019602225f, -0.980785280403230449f,  0.195090322016128268f,  0.831469612302545237f,
      -0.831469612302545237f, -0.195090322016128268f,  0.980785280403230449f, -0.555570233019602225f },
    {  0.382683432365089772f, -0.923879532511286756f,  0.923879532511286756f, -0.382683432365089772f,
      -0.382683432365089772f,  0.923879532511286756f, -0.923879532511286756f,  0.382683432365089772f },
    {  0.195090322016128268f, -0.555570233019602225f,  0.831469612302545237f, -0.980785280403230449f,
       0.980785280403230449f, -0.831469612302545237f,  0.555570233019602225f, -0.195090322016128268f },
};

__global__ __launch_bounds__(256, 6) void jpeg_decode_kernel(
    const float* __restrict__ yg,
    const float* __restrict__ cbg,
    const float* __restrict__ crg,
    const float* __restrict__ y_table,
    const float* __restrict__ c_table,
    const float* __restrict__ alpha,
    const float* __restrict__ dct,
    const float* __restrict__ shiftp,
    const float* __restrict__ matp,
    const int* __restrict__ factor_p,
    float* __restrict__ out)
{
    __shared__ float qY[64];        // y_table*factor*alpha
    __shared__ float qC[64];        // c_table*factor*alpha
    __shared__ float cosT[64];      // cos((2u+1)x pi/16) for runtime-v pass-1 reads
    __shared__ float matS[9];
    __shared__ float shiftS[3];
    __shared__ float pixY[16 * 256];
    __shared__ float pixCb[8 * 128];
    __shared__ float pixCr[8 * 128];

    const int tid = threadIdx.x;
    const int b   = blockIdx.z;

    // XCD-chunked swizzle: dispatch id % 8 == blockIdx.x on this grid, so
    // XCD k gets T in [k*128, (k+1)*128) = 16 contiguous row-stripes.
    const int wgid = blockIdx.x + TW_TILES * blockIdx.y;  // 0..1023
    const int T    = (wgid & 7) * 128 + (wgid >> 3);      // bijective
    const int tw   = T & 7;     // column chunk 0..7
    const int th   = T >> 3;    // row stripe  0..127

    // ---- setup: tables (threads 0..75) ----
    if (tid < 64) {
        const float f = (float)factor_p[0];
        qY[tid] = y_table[tid] * f * alpha[tid];
        qC[tid] = c_table[tid] * f * alpha[tid];
        cosT[tid] = dct[(tid >> 3) * 512 + (tid & 7) * 8];   // = CT[x][u]
    } else if (tid < 73) {
        matS[tid - 64] = matp[tid - 64];
    } else if (tid < 76) {
        shiftS[tid - 73] = shiftp[tid - 73];
    }
    __syncthreads();   // tables ready

    // per-thread pass-1 cosine column (runtime v)
    const int v = tid & 7;
    float cv[8];
#pragma unroll
    for (int y = 0; y < 8; y++) cv[y] = cosT[y * 8 + v];

    // ================= Y plane: 64 blocks (2 block-rows x 32) =================
    // thread owns (bh=0, bw, v) and (bh=1, bw, v); tile column = bw*8+v = tid
    {
        const int bw = tid >> 3;   // 0..31
        const size_t yBase =
            ((size_t)b * (256 * 256) + (size_t)(2 * th) * 256 + (size_t)tw * 32 + bw) * 64;
        const float* p0 = yg + yBase;
        const float* p1 = p0 + 256 * 64;   // next Y block-row, same column

        float t0[8], t1[8];
#pragma unroll
        for (int x = 0; x < 8; x++) {
            const float4 qa = *(const float4*)&qY[x * 8];
            const float4 qb = *(const float4*)&qY[x * 8 + 4];
            const float4 a0 = *(const float4*)(p0 + x * 8);
            const float4 b0 = *(const float4*)(p0 + x * 8 + 4);
            const float4 a1 = *(const float4*)(p1 + x * 8);
            const float4 b1 = *(const float4*)(p1 + x * 8 + 4);
            t0[x] = (a0.x * qa.x) * cv[0] + (a0.y * qa.y) * cv[1]
                  + (a0.z * qa.z) * cv[2] + (a0.w * qa.w) * cv[3]
                  + (b0.x * qb.x) * cv[4] + (b0.y * qb.y) * cv[5]
                  + (b0.z * qb.z) * cv[6] + (b0.w * qb.w) * cv[7];
            t1[x] = (a1.x * qa.x) * cv[0] + (a1.y * qa.y) * cv[1]
                  + (a1.z * qa.z) * cv[2] + (a1.w * qa.w) * cv[3]
                  + (b1.x * qb.x) * cv[4] + (b1.y * qb.y) * cv[5]
                  + (b1.z * qb.z) * cv[6] + (b1.w * qb.w) * cv[7];
        }
#pragma unroll
        for (int u = 0; u < 8; u++) {
            float s0 = 0.f, s1 = 0.f;
#pragma unroll
            for (int x = 0; x < 8; x++) { s0 += t0[x] * CT[x][u]; s1 += t1[x] * CT[x][u]; }
            pixY[u * 256 + tid]       = 0.25f * s0 + 128.0f;
            pixY[(8 + u) * 256 + tid] = 0.25f * s1 + 128.0f;
        }
    }

    // ============== chroma: 16 Cb + 16 Cr blocks, all 256 threads ==============
    // waves 0,1 -> Cb; waves 2,3 -> Cr (uniform per wave). chroma col = cpos.
    {
        const int cpos = tid & 127;
        const int cblk = cpos >> 3;            // 0..15
        const float* csrc = (tid >= 128) ? crg : cbg;
        const size_t cBase =
            ((size_t)b * (128 * 128) + (size_t)th * 128 + (size_t)tw * 16 + cblk) * 64;
        const float* pc = csrc + cBase;

        float tc[8];
#pragma unroll
        for (int x = 0; x < 8; x++) {
            const float4 qa = *(const float4*)&qC[x * 8];
            const float4 qb = *(const float4*)&qC[x * 8 + 4];
            const float4 a  = *(const float4*)(pc + x * 8);
            const float4 c  = *(const float4*)(pc + x * 8 + 4);
            tc[x] = (a.x * qa.x) * cv[0] + (a.y * qa.y) * cv[1]
                  + (a.z * qa.z) * cv[2] + (a.w * qa.w) * cv[3]
                  + (c.x * qb.x) * cv[4] + (c.y * qb.y) * cv[5]
                  + (c.z * qb.z) * cv[6] + (c.w * qb.w) * cv[7];
        }
        float* cdst = (tid >= 128) ? pixCr : pixCb;
#pragma unroll
        for (int u = 0; u < 8; u++) {
            float s = 0.f;
#pragma unroll
            for (int x = 0; x < 8; x++) s += tc[x] * CT[x][u];
            cdst[u * 128 + cpos] = 0.25f * s + 128.0f;
        }
    }
    __syncthreads();   // pixY / pixCb / pixCr ready

    // ---- fused upsample + color convert + clip + store ----
    // wave w stores rows {w, 4+w, 8+w, 12+w}; each store instruction is one
    // contiguous 1 KB row segment per plane.
    {
        const float s0 = shiftS[0], s1 = shiftS[1], s2 = shiftS[2];
        const float m0 = matS[0], m1 = matS[1], m2 = matS[2];
        const float m3 = matS[3], m4 = matS[4], m5 = matS[5];
        const float m6 = matS[6], m7 = matS[7], m8 = matS[8];
        const float inv255 = 1.0f / 255.0f;
        const size_t planeStride = (size_t)H * W;
        const size_t outBase = (size_t)b * 3 * planeStride;
        const int w    = tid >> 6;        // wave 0..3
        const int lane = tid & 63;
        const int c4   = lane * 4;        // 0..252

#pragma unroll
        for (int k = 0; k < 4; k++) {
            const int r = k * 4 + w;      // 0..15
            const float4 yv = *(const float4*)&pixY[r * 256 + c4];
            const int rc = r >> 1, cc = c4 >> 1;      // cc even -> 8B aligned
            const float2 cbv2 = *(const float2*)&pixCb[rc * 128 + cc];
            const float2 crv2 = *(const float2*)&pixCr[rc * 128 + cc];
            const float yy[4]  = { yv.x + s0, yv.y + s0, yv.z + s0, yv.w + s0 };
            const float cbv[2] = { cbv2.x + s1, cbv2.y + s1 };
            const float crv[2] = { crv2.x + s2, crv2.y + s2 };

            f32x4 R, G, Bv;
#pragma unroll
            for (int j = 0; j < 4; j++) {
                const int h2 = j >> 1;
                const float Yv = yy[j], Cb = cbv[h2], Cr = crv[h2];
                const float r_ = Yv * m0 + Cb * m3 + Cr * m6;
                const float g_ = Yv * m1 + Cb * m4 + Cr * m7;
                const float b_ = Yv * m2 + Cb * m5 + Cr * m8;
                R[j]  = fminf(fmaxf(r_, 0.0f), 255.0f) * inv255;
                G[j]  = fminf(fmaxf(g_, 0.0f), 255.0f) * inv255;
                Bv[j] = fminf(fmaxf(b_, 0.0f), 255.0f) * inv255;
            }

            const size_t row = (size_t)th * 16 + r;
            const size_t col = (size_t)tw * 256 + c4;
            const size_t o = outBase + row * W + col;
            *(f32x4*)(out + o)                    = R;
            *(f32x4*)(out + o + planeStride)      = G;
            *(f32x4*)(out + o + 2 * planeStride)  = Bv;
        }
    }
}

extern "C" void kernel_launch(void* const* d_in, const int* in_sizes, int n_in,
                              void* d_out, int out_size, void* d_ws, size_t ws_size,
                              hipStream_t stream) {
    (void)in_sizes; (void)n_in; (void)d_ws; (void)ws_size; (void)out_size;
    const float* yg      = (const float*)d_in[0];
    const float* cbg     = (const float*)d_in[1];
    const float* crg     = (const float*)d_in[2];
    const float* y_table = (const float*)d_in[3];
    const float* c_table = (const float*)d_in[4];
    const float* alpha   = (const float*)d_in[5];
    const float* dct     = (const float*)d_in[6];
    const float* shiftp  = (const float*)d_in[7];
    const float* matp    = (const float*)d_in[8];
    const int*   factor  = (const int*)d_in[11];
    float* outp = (float*)d_out;

    dim3 grid(TW_TILES, TH_TILES, 8);   // (8, 128, 8)
    jpeg_decode_kernel<<<grid, 256, 0, stream>>>(
        yg, cbg, crg, y_table, c_table, alpha, dct, shiftp, matp, factor, outp);
}